// Round 2
// baseline (661.406 us; speedup 1.0000x reference)
//
#include <hip/hip_runtime.h>
#include <math.h>

// Problem constants (B=1)
#define T_ 2048
#define D_ 1024
#define H_ 16
#define N_ 64
#define F_ 4096
#define NCHUNK 32
#define CLEN 64

typedef __attribute__((ext_vector_type(8))) short bf16x8;
typedef __attribute__((ext_vector_type(4))) float f32x4;
typedef __attribute__((address_space(3))) unsigned int lds_u32_t;
typedef __attribute__((address_space(1))) const unsigned int glb_u32_t;

static __device__ __forceinline__ float sigf(float x) { return 1.0f / (1.0f + __expf(-x)); }

static __device__ __forceinline__ ushort f2bf(float f) {
    union { float f; unsigned u; } c; c.f = f;
    unsigned r = (c.u + 0x7FFFu + ((c.u >> 16) & 1u)) >> 16;
    return (ushort)r;
}
static __device__ __forceinline__ float bf2f(ushort h) {
    union { unsigned u; float f; } c; c.u = ((unsigned)h) << 16;
    return c.f;
}

static __device__ __forceinline__ void st4(float* p, float4 v) { *(float4*)p = v; }
static __device__ __forceinline__ void st4(ushort* p, float4 v) {
    ushort4 o; o.x = f2bf(v.x); o.y = f2bf(v.y); o.z = f2bf(v.z); o.w = f2bf(v.w);
    *(ushort4*)p = o;
}

// ---------------------------------------------------------------------------
// RMSNorm: one block per token row. out = w * x * rsqrt(mean(x^2)+eps)
// ---------------------------------------------------------------------------
template <typename OutT>
__global__ __launch_bounds__(256) void rmsnorm_kernel(const float* __restrict__ x,
                                                      const float* __restrict__ w,
                                                      OutT* __restrict__ out,
                                                      float* __restrict__ last) {
    const int t = blockIdx.x;
    const int tid = threadIdx.x;
    const float4* xr = (const float4*)(x + (size_t)t * D_);
    float4 v = xr[tid];
    float ss = v.x * v.x + v.y * v.y + v.z * v.z + v.w * v.w;
    ss += __shfl_xor(ss, 1);
    ss += __shfl_xor(ss, 2);
    ss += __shfl_xor(ss, 4);
    ss += __shfl_xor(ss, 8);
    ss += __shfl_xor(ss, 16);
    ss += __shfl_xor(ss, 32);
    __shared__ float red[4];
    if ((tid & 63) == 0) red[tid >> 6] = ss;
    __syncthreads();
    float tot = red[0] + red[1] + red[2] + red[3];
    float scale = rsqrtf(tot * (1.0f / (float)D_) + 1e-6f);
    float4 wv = ((const float4*)w)[tid];
    float4 o;
    o.x = wv.x * v.x * scale;
    o.y = wv.y * v.y * scale;
    o.z = wv.z * v.z * scale;
    o.w = wv.w * v.w * scale;
    st4(out + (size_t)t * D_ + tid * 4, o);
    if (last != nullptr && t == T_ - 1) ((float4*)last)[tid] = o;
}

// ---------------------------------------------------------------------------
// Token shift -> six bf16 activation buffers (GEMM A operands).
// ---------------------------------------------------------------------------
__global__ __launch_bounds__(256) void shift_kernel(
    const float* __restrict__ xn, const float* __restrict__ x_prev,
    const float* __restrict__ cr, const float* __restrict__ cw, const float* __restrict__ ck,
    const float* __restrict__ cv, const float* __restrict__ ca, const float* __restrict__ cg,
    ushort* __restrict__ xr, ushort* __restrict__ xw, ushort* __restrict__ xk,
    ushort* __restrict__ xv, ushort* __restrict__ xa, ushort* __restrict__ xg) {
    const int i = blockIdx.x * 256 + threadIdx.x;  // float4 index over T*256
    const int t = i >> 8, j = i & 255;
    const float4* xn4 = (const float4*)xn;
    float4 cur = xn4[i];
    float4 prev = (t == 0) ? ((const float4*)x_prev)[j] : xn4[i - 256];
    float4 xx;
    xx.x = prev.x - cur.x;
    xx.y = prev.y - cur.y;
    xx.z = prev.z - cur.z;
    xx.w = prev.w - cur.w;
#define APPLY(dst, c)                                   \
    {                                                   \
        float4 cc = ((const float4*)c)[j];              \
        float4 o;                                       \
        o.x = cur.x + xx.x * cc.x;                      \
        o.y = cur.y + xx.y * cc.y;                      \
        o.z = cur.z + xx.z * cc.z;                      \
        o.w = cur.w + xx.w * cc.w;                      \
        st4(dst + (size_t)i * 4, o);                    \
    }
    APPLY(xr, cr)
    APPLY(xw, cw)
    APPLY(xk, ck)
    APPLY(xv, cv)
    APPLY(xa, ca)
    APPLY(xg, cg)
#undef APPLY
}

// ---------------------------------------------------------------------------
// Merged weight transpose + cast: all 15 weights in ONE launch.
// ---------------------------------------------------------------------------
struct TDesc { const float* in; ushort* out; int K, N, off; };
struct TPack { TDesc d[15]; };

__global__ __launch_bounds__(256) void transpose_cast_multi(TPack p) {
    __shared__ float tile[32][33];
    const int bid = blockIdx.x;
    int di = 0;
#pragma unroll
    for (int i = 1; i < 15; i++)
        if (bid >= p.d[i].off) di = i;
    const TDesc d = p.d[di];
    const int local = bid - d.off;
    const int nt = d.N >> 5;
    const int bx = local % nt, by = local / nt;
    const int tx = threadIdx.x & 31, ty = threadIdx.x >> 5;  // 32 x 8
    const int n0 = bx * 32, k0 = by * 32;
#pragma unroll
    for (int i = 0; i < 4; i++)
        tile[ty + i * 8][tx] = d.in[(size_t)(k0 + ty + i * 8) * d.N + n0 + tx];
    __syncthreads();
#pragma unroll
    for (int i = 0; i < 4; i++)
        d.out[(size_t)(n0 + ty + i * 8) * d.K + k0 + tx] = f2bf(tile[tx][ty + i * 8]);
}

// ---------------------------------------------------------------------------
// bf16 MFMA GEMM, 2-phase double-buffered global_load_lds pipeline.
// 128x128 tile, 4 waves 2x2, BK=32, mfma_f32_16x16x32_bf16. Per K-step:
// issue next tile's DMA FIRST, then ds_read+MFMA current (load latency hides
// under compute), then ONE __syncthreads (vmcnt drain only sees the residual).
// Non-atomic; epi: 0 none, 1 += res (fused residual, res may alias C idx-wise).
// ---------------------------------------------------------------------------
template <typename OutT>
__global__ __launch_bounds__(256) void mfma_gemm(
    const ushort* __restrict__ A, const ushort* __restrict__ BT, OutT* __restrict__ C,
    const float* res, int M, int Ntot, int K, int epi) {
    __shared__ ushort As[2][128 * 32];
    __shared__ ushort Bs[2][128 * 32];
    const int tid = threadIdx.x;
    const int wave = tid >> 6, lane = tid & 63;
    const int wr = wave >> 1, wc = wave & 1;
    const int lrow = lane & 15, quad = lane >> 4;
    const int m0 = blockIdx.y * 128, n0 = blockIdx.x * 128;
    const int srow = lane >> 2;
    const int scol = (lane & 3) << 3;

    f32x4 acc[4][4] = {};

    auto stage = [&](int buf, int kk) {
#pragma unroll
        for (int j = 0; j < 2; j++) {
            const int chunk = 2 * wave + j;  // 0..7
            const ushort* ga = A + (size_t)(m0 + chunk * 16 + srow) * K + kk + scol;
            __builtin_amdgcn_global_load_lds((glb_u32_t*)ga,
                                             (lds_u32_t*)&As[buf][chunk * 512], 16, 0, 0);
            const int brow = n0 + chunk * 16 + srow;
            if (brow < Ntot) {
                const ushort* gb = BT + (size_t)brow * K + kk + scol;
                __builtin_amdgcn_global_load_lds((glb_u32_t*)gb,
                                                 (lds_u32_t*)&Bs[buf][chunk * 512], 16, 0, 0);
            }
        }
    };

    stage(0, 0);
    __syncthreads();
    int cur = 0;
    for (int k0 = 0; k0 < K; k0 += 32) {
        if (k0 + 32 < K) stage(cur ^ 1, k0 + 32);
        bf16x8 af[4], bfr[4];
#pragma unroll
        for (int mi = 0; mi < 4; mi++)
            af[mi] = *(const bf16x8*)&As[cur][(wr * 64 + mi * 16 + lrow) * 32 + quad * 8];
#pragma unroll
        for (int ni = 0; ni < 4; ni++)
            bfr[ni] = *(const bf16x8*)&Bs[cur][(wc * 64 + ni * 16 + lrow) * 32 + quad * 8];
#pragma unroll
        for (int mi = 0; mi < 4; mi++)
#pragma unroll
            for (int ni = 0; ni < 4; ni++)
                acc[mi][ni] = __builtin_amdgcn_mfma_f32_16x16x32_bf16(af[mi], bfr[ni], acc[mi][ni], 0, 0, 0);
        __syncthreads();
        cur ^= 1;
    }

#pragma unroll
    for (int mi = 0; mi < 4; mi++) {
#pragma unroll
        for (int r = 0; r < 4; r++) {
            const int row = m0 + wr * 64 + mi * 16 + quad * 4 + r;
#pragma unroll
            for (int ni = 0; ni < 4; ni++) {
                const int col = n0 + wc * 64 + ni * 16 + lrow;
                if (col < Ntot) {
                    const size_t idx = (size_t)row * Ntot + col;
                    float val = acc[mi][ni][r];
                    if (epi == 1) val += res[idx];
                    if constexpr (sizeof(OutT) == 2) C[idx] = (OutT)f2bf(val);
                    else C[idx] = (OutT)val;
                }
            }
        }
    }
}

// ---------------------------------------------------------------------------
// Multi-GEMM: z-indexed descriptors, same 2-phase pipeline. Non-atomic.
// epi: 0 none, 3 tanh, 4 sig, 5 sig(bias+v), 6 exp(-e^-.5*sig(bias+v)),
//      7 res+(res2-res)*sig(bias+v)
// ---------------------------------------------------------------------------
struct MMDesc {
    const ushort* A; const ushort* BT;
    float* Cf; ushort* Cb;
    const float* res; const float* res2; const float* bias;
    int Ntot, K, epi;
};
template <int NZ>
struct MMPack { MMDesc d[NZ]; };

template <int NZ>
__global__ __launch_bounds__(256) void mfma_gemm_multi(MMPack<NZ> p) {
    const MMDesc d = p.d[blockIdx.z];
    const int n0 = blockIdx.x * 128;
    if (n0 >= d.Ntot) return;  // uniform across block; no barrier crossed yet
    __shared__ ushort As[2][128 * 32];
    __shared__ ushort Bs[2][128 * 32];
    const int tid = threadIdx.x;
    const int wave = tid >> 6, lane = tid & 63;
    const int wr = wave >> 1, wc = wave & 1;
    const int lrow = lane & 15, quad = lane >> 4;
    const int m0 = blockIdx.y * 128;
    const int srow = lane >> 2;
    const int scol = (lane & 3) << 3;
    const int K = d.K, Ntot = d.Ntot;

    f32x4 acc[4][4] = {};

    auto stage = [&](int buf, int kk) {
#pragma unroll
        for (int j = 0; j < 2; j++) {
            const int chunk = 2 * wave + j;
            const ushort* ga = d.A + (size_t)(m0 + chunk * 16 + srow) * K + kk + scol;
            __builtin_amdgcn_global_load_lds((glb_u32_t*)ga,
                                             (lds_u32_t*)&As[buf][chunk * 512], 16, 0, 0);
            const int brow = n0 + chunk * 16 + srow;
            if (brow < Ntot) {
                const ushort* gb = d.BT + (size_t)brow * K + kk + scol;
                __builtin_amdgcn_global_load_lds((glb_u32_t*)gb,
                                                 (lds_u32_t*)&Bs[buf][chunk * 512], 16, 0, 0);
            }
        }
    };

    stage(0, 0);
    __syncthreads();
    int cur = 0;
    for (int k0 = 0; k0 < K; k0 += 32) {
        if (k0 + 32 < K) stage(cur ^ 1, k0 + 32);
        bf16x8 af[4], bfr[4];
#pragma unroll
        for (int mi = 0; mi < 4; mi++)
            af[mi] = *(const bf16x8*)&As[cur][(wr * 64 + mi * 16 + lrow) * 32 + quad * 8];
#pragma unroll
        for (int ni = 0; ni < 4; ni++)
            bfr[ni] = *(const bf16x8*)&Bs[cur][(wc * 64 + ni * 16 + lrow) * 32 + quad * 8];
#pragma unroll
        for (int mi = 0; mi < 4; mi++)
#pragma unroll
            for (int ni = 0; ni < 4; ni++)
                acc[mi][ni] = __builtin_amdgcn_mfma_f32_16x16x32_bf16(af[mi], bfr[ni], acc[mi][ni], 0, 0, 0);
        __syncthreads();
        cur ^= 1;
    }

#pragma unroll
    for (int mi = 0; mi < 4; mi++) {
#pragma unroll
        for (int r = 0; r < 4; r++) {
            const int row = m0 + wr * 64 + mi * 16 + quad * 4 + r;
#pragma unroll
            for (int ni = 0; ni < 4; ni++) {
                const int col = n0 + wc * 64 + ni * 16 + lrow;
                if (col < Ntot) {
                    const size_t idx = (size_t)row * Ntot + col;
                    float val = acc[mi][ni][r];
                    switch (d.epi) {
                        case 3: val = tanhf(val); break;
                        case 4: val = sigf(val); break;
                        case 5: val = sigf(d.bias[col] + val); break;
                        case 6: val = __expf(-0.60653065971263342f * sigf(d.bias[col] + val)); break;
                        case 7: {
                            float vr = d.res[idx];
                            val = vr + (d.res2[idx] - vr) * sigf(d.bias[col] + val);
                        } break;
                        default: break;
                    }
                    if (d.Cb) d.Cb[idx] = f2bf(val);
                    else d.Cf[idx] = val;
                }
            }
        }
    }
}

// ---------------------------------------------------------------------------
// kk = normalize_per_head(k * k_k); mb = -kk*a_sig; k *= (1+(a-1)*k_a).
// ---------------------------------------------------------------------------
__global__ __launch_bounds__(256) void kk_kernel(float* __restrict__ k,
                                                 const float* __restrict__ a_sig,
                                                 const float* __restrict__ k_k,
                                                 const float* __restrict__ k_a,
                                                 float* __restrict__ kk,
                                                 float* __restrict__ mb) {
    const int b = blockIdx.x * 4 + (threadIdx.x >> 6);
    const int t = b >> 4, h = b & 15;
    const int lane = threadIdx.x & 63;
    const size_t idx = (size_t)t * D_ + h * N_ + lane;
    const int wi = h * N_ + lane;
    const float kraw = k[idx];
    const float kv = kraw * k_k[wi];
    float ss = kv * kv;
    ss += __shfl_xor(ss, 1);
    ss += __shfl_xor(ss, 2);
    ss += __shfl_xor(ss, 4);
    ss += __shfl_xor(ss, 8);
    ss += __shfl_xor(ss, 16);
    ss += __shfl_xor(ss, 32);
    const float nrm = fmaxf(sqrtf(ss), 1e-12f);
    const float kkn = kv / nrm;
    kk[idx] = kkn;
    mb[idx] = -kkn * a_sig[idx];
    k[idx] = kraw * (1.0f + (a_sig[idx] - 1.0f) * k_a[wi]);
}

// ---------------------------------------------------------------------------
// Chunked scan pass 1: lane = row, register state; reg-staged 2-slot LDS ring.
// ---------------------------------------------------------------------------
#define FOR16(M) M(0) M(1) M(2) M(3) M(4) M(5) M(6) M(7) \
                 M(8) M(9) M(10) M(11) M(12) M(13) M(14) M(15)

__global__ __launch_bounds__(64, 1) void scan_pass1(
    const float* __restrict__ gR, const float* __restrict__ gD, const float* __restrict__ gK,
    const float* __restrict__ gV, const float* __restrict__ gKK, const float* __restrict__ gMB,
    float* __restrict__ Pbuf, float* __restrict__ Lbuf,
    float* __restrict__ zbuf, float* __restrict__ olbuf) {
    const int bid = blockIdx.x;
    const bool isp = bid >= NCHUNK * H_;  // role = high bit
    const int sub = isp ? bid - NCHUNK * H_ : bid;
    const int h = sub & 15;
    const int c = sub >> 4;
    const int lane = threadIdx.x;  // row index
    const int hb = h * N_;
    const int t0 = c * CLEN;
    const int tend = t0 + CLEN - 1;

    __shared__ __align__(16) unsigned char ring[2 * 2048];

    const int rsel = lane >> 4;
    const int sub4 = (lane & 15) << 2;
    const float* p1 = (rsel == 0 ? gR : rsel == 1 ? gD : rsel == 2 ? gK : gKK)
                      + (size_t)t0 * D_ + hb + sub4;
    const float* p2 = (rsel == 1 ? gV : gMB) + (size_t)t0 * D_ + hb + sub4;

    const float fid = isp ? 1.0f : 0.0f;
#define DECL(q) f32x4 s##q = {(lane == 4 * q + 0) ? fid : 0.0f, \
                              (lane == 4 * q + 1) ? fid : 0.0f, \
                              (lane == 4 * q + 2) ? fid : 0.0f, \
                              (lane == 4 * q + 3) ? fid : 0.0f};
    FOR16(DECL)
#undef DECL

    float* __restrict__ dotOut = isp ? zbuf : olbuf;

    float4 r0a, r0b, r1a, r1b, r2a, r2b, r3a, r3b;

#define LOADQ(qa, qb, tt) {                                                  \
        const size_t _adv = (size_t)((tt) - t0) * D_;                        \
        qa = *(const float4*)(p1 + _adv);                                    \
        qb = *(const float4*)(p2 + _adv); }
#define WRITEQ(sl, qa, qb) {                                                 \
        *(float4*)(ring + (sl) * 2048 + lane * 16) = qa;                     \
        *(float4*)(ring + (sl) * 2048 + 1024 + lane * 16) = qb; }
#define PA(q) { const f32x4 kk4 = sKKr[q]; sacc += s##q * kk4; }
#define PB(q) {                                                   \
        const f32x4 d4 = sDr[q];                                  \
        const f32x4 k4 = sKr[q];                                  \
        const f32x4 m4 = sMBr[q];                                 \
        const f32x4 r4 = sRr[q];                                  \
        s##q = s##q * d4 + (m4 * sap + k4 * vv);                  \
        oacc += s##q * r4;                                        \
    }
#define COMPUTE(sl, tt) {                                                    \
        const unsigned char* sb = (const unsigned char*)ring + (sl) * 2048;  \
        const f32x4* sRr = (const f32x4*)(sb);                               \
        const f32x4* sDr = (const f32x4*)(sb + 256);                         \
        const f32x4* sKr = (const f32x4*)(sb + 512);                         \
        const f32x4* sKKr = (const f32x4*)(sb + 768);                        \
        const f32x4* sMBr = (const f32x4*)(sb + 1024);                       \
        const float* sVr = (const float*)(sb + 1280);                        \
        f32x4 sacc = {0.f, 0.f, 0.f, 0.f};                                   \
        FOR16(PA)                                                            \
        const float sap = (sacc.x + sacc.y) + (sacc.z + sacc.w);             \
        const float vv = isp ? 0.0f : sVr[lane];                             \
        f32x4 oacc = {0.f, 0.f, 0.f, 0.f};                                   \
        FOR16(PB)                                                            \
        dotOut[(size_t)(tt) * D_ + hb + lane] =                              \
            (oacc.x + oacc.y) + (oacc.z + oacc.w); }

    // prologue: 4-deep register pipeline; slot0 primed with t0
    LOADQ(r0a, r0b, t0)
    LOADQ(r1a, r1b, t0 + 1)
    LOADQ(r2a, r2b, t0 + 2)
    LOADQ(r3a, r3b, t0 + 3)
    WRITEQ(0, r0a, r0b)

    for (int t = t0; t < t0 + CLEN; t += 4) {
        WRITEQ(1, r1a, r1b)                                    // data t+1
        LOADQ(r0a, r0b, (t + 4 > tend ? tend : t + 4))
        COMPUTE(0, t)
        WRITEQ(0, r2a, r2b)                                    // data t+2
        LOADQ(r1a, r1b, (t + 5 > tend ? tend : t + 5))
        COMPUTE(1, t + 1)
        WRITEQ(1, r3a, r3b)                                    // data t+3
        LOADQ(r2a, r2b, (t + 6 > tend ? tend : t + 6))
        COMPUTE(0, t + 2)
        WRITEQ(0, r0a, r0b)                                    // data t+4
        LOADQ(r3a, r3b, (t + 7 > tend ? tend : t + 7))
        COMPUTE(1, t + 3)
    }
#undef COMPUTE
#undef PB
#undef PA
#undef WRITEQ
#undef LOADQ

    float* __restrict__ sd = isp ? Pbuf : Lbuf;
    const size_t base = ((size_t)c * 16 + h) * 4096 + (size_t)lane * 64;
#define ST(q) *(f32x4*)(sd + base + 4 * q) = s##q;
    FOR16(ST)
#undef ST
}

// ---------------------------------------------------------------------------
// Serial chunk combine: S_{c+1} = S_c @ P_c + L_c, S_0 = state_in.
// ---------------------------------------------------------------------------
__global__ __launch_bounds__(256) void scan_combine(
    const float* __restrict__ state_in, const float* __restrict__ Pbuf,
    const float* __restrict__ Lbuf, float* __restrict__ SstT, float* __restrict__ state_out) {
    const int h = blockIdx.x >> 2, rg = blockIdx.x & 3;
    const int tid = threadIdx.x;
    const int i = tid >> 4, j4 = (tid & 15) << 2;
    const int gi = rg * 16 + i;
    __shared__ float Sl[16][68];
    __shared__ float Pl[64][68];

    float4 sv = *(const float4*)(state_in + (size_t)h * 4096 + gi * 64 + j4);
    *(float4*)&Sl[i][j4] = sv;
    __syncthreads();

    for (int c = 0; c < NCHUNK; c++) {
        const size_t cb = ((size_t)c * 16 + h) * 4096;
        float4 scur = *(const float4*)&Sl[i][j4];
        SstT[cb + (size_t)(j4 + 0) * 64 + gi] = scur.x;
        SstT[cb + (size_t)(j4 + 1) * 64 + gi] = scur.y;
        SstT[cb + (size_t)(j4 + 2) * 64 + gi] = scur.z;
        SstT[cb + (size_t)(j4 + 3) * 64 + gi] = scur.w;
#pragma unroll
        for (int q = 0; q < 4; q++) {
            const int pr = (tid >> 4) + q * 16;
            *(float4*)&Pl[pr][j4] = *(const float4*)(Pbuf + cb + (size_t)pr * 64 + j4);
        }
        __syncthreads();
        float4 acc = *(const float4*)(Lbuf + cb + (size_t)gi * 64 + j4);
#pragma unroll 8
        for (int m = 0; m < 64; m++) {
            const float smv = Sl[i][m];
            const float4 p4 = *(const float4*)&Pl[m][j4];
            acc.x = fmaf(smv, p4.x, acc.x);
            acc.y = fmaf(smv, p4.y, acc.y);
            acc.z = fmaf(smv, p4.z, acc.z);
            acc.w = fmaf(smv, p4.w, acc.w);
        }
        __syncthreads();
        *(float4*)&Sl[i][j4] = acc;
        __syncthreads();
    }
    *(float4*)(state_out + (size_t)h * 4096 + gi * 64 + j4) = *(const float4*)&Sl[i][j4];
}

// ---------------------------------------------------------------------------
// Fix pass: o[t] = o_local[t] + S_start_c @ z[t] (per head).
// ---------------------------------------------------------------------------
__global__ __launch_bounds__(256) void scan_fix(
    const float* __restrict__ zbuf, const float* __restrict__ olbuf,
    const float* __restrict__ SstT, float* __restrict__ o) {
    const int tg = blockIdx.x >> 4, h = blockIdx.x & 15;
    const int hb = h * N_;
    const int tid = threadIdx.x;
    const int tok = tid >> 4, i4 = (tid & 15) << 2;
    const int tbase = tg * 16;
    const int c = tbase >> 6;
    __shared__ float zl[16][68];
    __shared__ float Sl[64][68];

    *(float4*)&zl[tok][i4] = *(const float4*)(zbuf + (size_t)(tbase + tok) * D_ + hb + i4);
    const size_t cb = ((size_t)c * 16 + h) * 4096;
#pragma unroll
    for (int q = 0; q < 4; q++) {
        const int jr = (tid >> 4) + q * 16;
        *(float4*)&Sl[jr][i4] = *(const float4*)(SstT + cb + (size_t)jr * 64 + i4);
    }
    __syncthreads();
    float4 acc = *(const float4*)(olbuf + (size_t)(tbase + tok) * D_ + hb + i4);
#pragma unroll 8
    for (int j = 0; j < 64; j++) {
        const float zv = zl[tok][j];
        const float4 p4 = *(const float4*)&Sl[j][i4];
        acc.x = fmaf(zv, p4.x, acc.x);
        acc.y = fmaf(zv, p4.y, acc.y);
        acc.z = fmaf(zv, p4.z, acc.z);
        acc.w = fmaf(zv, p4.w, acc.w);
    }
    *(float4*)(o + (size_t)(tbase + tok) * D_ + hb + i4) = acc;
}

// ---------------------------------------------------------------------------
// bonus + gate: og = bf16((o + (sum_j r*k*r_k) * v) * g).
// ---------------------------------------------------------------------------
__global__ __launch_bounds__(256) void bonus_kernel(const float* __restrict__ o,
                                                    const float* __restrict__ r,
                                                    const float* __restrict__ k,
                                                    const float* __restrict__ v,
                                                    const float* __restrict__ g,
                                                    const float* __restrict__ r_k,
                                                    ushort* __restrict__ og) {
    const int b = blockIdx.x * 4 + (threadIdx.x >> 6);
    const int t = b >> 4, h = b & 15;
    const int lane = threadIdx.x & 63;
    const size_t idx = (size_t)t * D_ + h * N_ + lane;
    float c = r[idx] * k[idx] * r_k[h * N_ + lane];
    c += __shfl_xor(c, 1);
    c += __shfl_xor(c, 2);
    c += __shfl_xor(c, 4);
    c += __shfl_xor(c, 8);
    c += __shfl_xor(c, 16);
    c += __shfl_xor(c, 32);
    const float on = o[idx] + c * v[idx];
    og[idx] = f2bf(on * g[idx]);
}

// H[t,j] = silu(Z[t,j]) * Z[t,j+4096]  (Z = merged [gate|up], [T,8192] bf16)
__global__ __launch_bounds__(256) void mulz_kernel(const ushort* __restrict__ Z,
                                                   ushort* __restrict__ Hb) {
    const int idx = blockIdx.x * 256 + threadIdx.x;  // ushort4 index over T*1024
    const int t = idx >> 10;
    const int j = (idx & 1023) << 2;
    const ushort4 zg = *(const ushort4*)(Z + (size_t)t * 8192 + j);
    const ushort4 zu = *(const ushort4*)(Z + (size_t)t * 8192 + 4096 + j);
    ushort4 o;
    float g0 = bf2f(zg.x), g1 = bf2f(zg.y), g2 = bf2f(zg.z), g3 = bf2f(zg.w);
    o.x = f2bf(g0 * sigf(g0) * bf2f(zu.x));
    o.y = f2bf(g1 * sigf(g1) * bf2f(zu.y));
    o.z = f2bf(g2 * sigf(g2) * bf2f(zu.z));
    o.w = f2bf(g3 * sigf(g3) * bf2f(zu.w));
    *(ushort4*)(Hb + (size_t)t * 4096 + j) = o;
}

// ---------------------------------------------------------------------------
extern "C" void kernel_launch(void* const* d_in, const int* in_sizes, int n_in,
                              void* d_out, int out_size, void* d_ws, size_t ws_size,
                              hipStream_t stream) {
    const float* x      = (const float*)d_in[0];
    const float* x_prev = (const float*)d_in[1];
    const float* v_first= (const float*)d_in[2];
    const float* state  = (const float*)d_in[3];
    const float* ln1_w  = (const float*)d_in[4];
    const float* ln2_w  = (const float*)d_in[5];
    const float* x_r    = (const float*)d_in[6];
    const float* x_w    = (const float*)d_in[7];
    const float* x_k    = (const float*)d_in[8];
    const float* x_v    = (const float*)d_in[9];
    const float* x_a    = (const float*)d_in[10];
    const float* x_g    = (const float*)d_in[11];
    const float* w0     = (const float*)d_in[12];
    const float* w1     = (const float*)d_in[13];
    const float* w2     = (const float*)d_in[14];
    const float* a0     = (const float*)d_in[15];
    const float* a1     = (const float*)d_in[16];
    const float* a2     = (const float*)d_in[17];
    const float* v0     = (const float*)d_in[18];
    const float* v1     = (const float*)d_in[19];
    const float* v2     = (const float*)d_in[20];
    const float* g1     = (const float*)d_in[21];
    const float* g2     = (const float*)d_in[22];
    const float* k_k    = (const float*)d_in[23];
    const float* k_a    = (const float*)d_in[24];
    const float* r_k    = (const float*)d_in[25];
    const float* R_     = (const float*)d_in[26];
    const float* K_     = (const float*)d_in[27];
    const float* V_     = (const float*)d_in[28];
    const float* O_     = (const float*)d_in[29];
    const float* gate_w = (const float*)d_in[30];
    const float* up_w   = (const float*)d_in[31];
    const float* down_w = (const float*)d_in[32];

    float* ws = (float*)d_ws;
    const size_t U = (size_t)T_ * D_;  // 2M floats
    float* u_r  = ws;
    float* u_k  = ws + 1 * U;
    float* u_v  = ws + 2 * U;
    float* u_dc = ws + 3 * U;   // decay; later SstT
    float* u_kk = ws + 4 * U;   // kk;    later o (fix output)
    float* u_mb = ws + 5 * U;   // -kk*a
    float* u_g  = ws + 6 * U;
    float* u_ao = ws + 7 * U;   // a_sig; later Pbuf
    ushort* XB = (ushort*)(ws + 8 * U);
    const size_t TD = U;
    ushort* XR = XB + 0 * TD;
    ushort* XW = XB + 1 * TD;
    ushort* XK = XB + 2 * TD;
    ushort* XV = XB + 3 * TD;
    ushort* XA = XB + 4 * TD;
    ushort* XG = XB + 5 * TD;
    ushort* XM   = XB + 0 * TD;        // reuse XR after r-GEMM
    ushort* OG   = XB + 1 * TD;        // reuse XW after w-LoRA1
    ushort* Hbuf = XB + 2 * TD;        // MLP hidden, [T,F] bf16
    ushort* Zbuf = (ushort*)ws;        // merged [gate|up] [T,2F] bf16
    float* Pbuf  = u_ao;
    float* Lbuf  = (float*)XB;
    float* zbuf  = (float*)(XB + 2 * TD);
    float* olbuf = (float*)(XB + 4 * TD);
    float* SstT  = u_dc;
    float* obuf  = u_kk;
    ushort* WT = (ushort*)(ws + 11 * U);
    const size_t DD = (size_t)D_ * D_;
    const size_t DF = (size_t)D_ * F_;
    ushort* WTR = WT;
    ushort* WTK = WTR + DD;
    ushort* WTV = WTK + DD;
    ushort* WTO = WTV + DD;
    ushort* WTG = WTO + DD;
    ushort* WTU = WTG + DF;
    ushort* WTD = WTU + DF;
    ushort* WTw1 = WTD + DF;
    ushort* WTw2 = WTw1 + 64 * 1024;
    ushort* WTa1 = WTw2 + 64 * 1024;
    ushort* WTa2 = WTa1 + 64 * 1024;
    ushort* WTv1 = WTa2 + 64 * 1024;
    ushort* WTv2 = WTv1 + 32 * 1024;
    ushort* WTg1 = WTv2 + 32 * 1024;
    ushort* WTg2 = WTg1 + 128 * 1024;
    ushort* Lw = WTg2 + 128 * 1024;
    ushort* La = Lw + (size_t)T_ * 64;
    ushort* Lv = La + (size_t)T_ * 64;
    ushort* Lg = Lv + (size_t)T_ * 32;

    float* out_x = (float*)d_out;
    float* out_xn_last = out_x + (size_t)T_ * D_;
    float* out_state = out_xn_last + D_;

    // --- all 15 weight transposes in ONE launch ---
    TPack tp;
    int toff = 0, ti = 0;
    auto addT = [&](const float* in, ushort* out, int K, int N) {
        tp.d[ti].in = in; tp.d[ti].out = out; tp.d[ti].K = K; tp.d[ti].N = N; tp.d[ti].off = toff;
        toff += (N / 32) * (K / 32); ++ti;
    };
    addT(R_, WTR, D_, D_);
    addT(K_, WTK, D_, D_);
    addT(V_, WTV, D_, D_);
    addT(O_, WTO, D_, D_);
    addT(gate_w, WTG, D_, F_);
    addT(up_w, WTU, D_, F_);
    addT(down_w, WTD, F_, D_);
    addT(w1, WTw1, D_, 64);
    addT(w2, WTw2, 64, D_);
    addT(a1, WTa1, D_, 64);
    addT(a2, WTa2, 64, D_);
    addT(v1, WTv1, D_, 32);
    addT(v2, WTv2, 32, D_);
    addT(g1, WTg1, D_, 128);
    addT(g2, WTg2, 128, D_);
    transpose_cast_multi<<<toff, 256, 0, stream>>>(tp);

    // 1. ln1 -> xn (in d_out) + xn_last
    rmsnorm_kernel<float><<<T_, 256, 0, stream>>>(x, ln1_w, out_x, out_xn_last);
    // 2. token shift -> bf16 xr..xg
    shift_kernel<<<T_, 256, 0, stream>>>(out_x, x_prev, x_r, x_w, x_k, x_v, x_a, x_g,
                                         XR, XW, XK, XV, XA, XG);
    // 3-6. r/k/v (full-K, non-atomic) + 4 LoRA stage-1 GEMMs in ONE launch
    auto mkmm = [](const ushort* A, const ushort* BT, float* Cf, ushort* Cb,
                   const float* res, const float* res2, const float* bias,
                   int Ntot, int K, int epi) {
        MMDesc m{A, BT, Cf, Cb, res, res2, bias, Ntot, K, epi};
        return m;
    };
    MMPack<7> pa;
    pa.d[0] = mkmm(XR, WTR, u_r, nullptr, nullptr, nullptr, nullptr, D_, D_, 0);
    pa.d[1] = mkmm(XK, WTK, u_k, nullptr, nullptr, nullptr, nullptr, D_, D_, 0);
    pa.d[2] = mkmm(XV, WTV, u_v, nullptr, nullptr, nullptr, nullptr, D_, D_, 0);
    pa.d[3] = mkmm(XW, WTw1, nullptr, Lw, nullptr, nullptr, nullptr, 64,  D_, 3);  // tanh
    pa.d[4] = mkmm(XA, WTa1, nullptr, La, nullptr, nullptr, nullptr, 64,  D_, 0);
    pa.d[5] = mkmm(XV, WTv1, nullptr, Lv, nullptr, nullptr, nullptr, 32,  D_, 0);
    pa.d[6] = mkmm(XG, WTg1, nullptr, Lg, nullptr, nullptr, nullptr, 128, D_, 4);  // sigmoid
    mfma_gemm_multi<7><<<dim3(8, 16, 7), 256, 0, stream>>>(pa);
    // 7. LoRA stage-2 fused epilogues, ONE launch
    MMPack<4> pb;
    pb.d[0] = mkmm(Lw, WTw2, u_dc, nullptr, nullptr, nullptr, w0, D_, 64,  6);  // decay
    pb.d[1] = mkmm(La, WTa2, u_ao, nullptr, nullptr, nullptr, a0, D_, 64,  5);  // a_sig
    pb.d[2] = mkmm(Lv, WTv2, u_v,  nullptr, u_v, v_first,     v0, D_, 32,  7);  // v lerp
    pb.d[3] = mkmm(Lg, WTg2, u_g,  nullptr, nullptr, nullptr, nullptr, D_, 128, 0);  // g
    mfma_gemm_multi<4><<<dim3(8, 16, 4), 256, 0, stream>>>(pb);
    // 8. kk / mb / k-mod
    kk_kernel<<<T_ * H_ / 4, 256, 0, stream>>>(u_k, u_ao, k_k, k_a, u_kk, u_mb);
    // 9. chunked scan
    scan_pass1<<<NCHUNK * H_ * 2, 64, 0, stream>>>(u_r, u_dc, u_k, u_v, u_kk, u_mb,
                                                   Pbuf, Lbuf, zbuf, olbuf);
    scan_combine<<<H_ * 4, 256, 0, stream>>>(state, Pbuf, Lbuf, SstT, out_state);
    scan_fix<<<(T_ / 16) * H_, 256, 0, stream>>>(zbuf, olbuf, SstT, obuf);
    // 10. bonus + gate -> OG bf16
    bonus_kernel<<<T_ * H_ / 4, 256, 0, stream>>>(obuf, u_r, u_k, u_v, u_g, r_k, OG);
    // 11. x1 = x + og@O_ : fused residual, non-atomic (no memcpy needed)
    mfma_gemm<float><<<dim3(8, 16), 256, 0, stream>>>(OG, WTO, out_x, x, T_, D_, D_, 1);
    // 12. ln2 -> xm bf16
    rmsnorm_kernel<ushort><<<T_, 256, 0, stream>>>(out_x, ln2_w, XM, nullptr);
    // 13. MLP: merged gate|up (N=8192), swiglu, down with fused += residual
    mfma_gemm<ushort><<<dim3(64, 16), 256, 0, stream>>>(XM, WTG, Zbuf, nullptr, T_, 2 * F_, D_, 0);
    mulz_kernel<<<(T_ * (F_ / 4)) / 256, 256, 0, stream>>>(Zbuf, Hbuf);
    mfma_gemm<float><<<dim3(8, 16), 256, 0, stream>>>(Hbuf, WTD, out_x, out_x, T_, D_, F_, 1);
}

// Round 3
// 594.445 us; speedup vs baseline: 1.1126x; 1.1126x over previous
//
#include <hip/hip_runtime.h>
#include <math.h>

// Problem constants (B=1)
#define T_ 2048
#define D_ 1024
#define H_ 16
#define N_ 64
#define F_ 4096
#define NCHUNK 32
#define CLEN 64

typedef __attribute__((ext_vector_type(8))) short bf16x8;
typedef __attribute__((ext_vector_type(4))) float f32x4;
typedef __attribute__((address_space(3))) unsigned int lds_u32_t;
typedef __attribute__((address_space(1))) const unsigned int glb_u32_t;

static __device__ __forceinline__ float sigf(float x) { return 1.0f / (1.0f + __expf(-x)); }

static __device__ __forceinline__ ushort f2bf(float f) {
    union { float f; unsigned u; } c; c.f = f;
    unsigned r = (c.u + 0x7FFFu + ((c.u >> 16) & 1u)) >> 16;
    return (ushort)r;
}
static __device__ __forceinline__ float bf2f(ushort h) {
    union { unsigned u; float f; } c; c.u = ((unsigned)h) << 16;
    return c.f;
}

static __device__ __forceinline__ void st4(float* p, float4 v) { *(float4*)p = v; }
static __device__ __forceinline__ void st4(ushort* p, float4 v) {
    ushort4 o; o.x = f2bf(v.x); o.y = f2bf(v.y); o.z = f2bf(v.z); o.w = f2bf(v.w);
    *(ushort4*)p = o;
}

// ---------------------------------------------------------------------------
// RMSNorm: one block per token row. out = w * x * rsqrt(mean(x^2)+eps)
// ---------------------------------------------------------------------------
template <typename OutT>
__global__ __launch_bounds__(256) void rmsnorm_kernel(const float* __restrict__ x,
                                                      const float* __restrict__ w,
                                                      OutT* __restrict__ out,
                                                      float* __restrict__ last) {
    const int t = blockIdx.x;
    const int tid = threadIdx.x;
    const float4* xr = (const float4*)(x + (size_t)t * D_);
    float4 v = xr[tid];
    float ss = v.x * v.x + v.y * v.y + v.z * v.z + v.w * v.w;
    ss += __shfl_xor(ss, 1);
    ss += __shfl_xor(ss, 2);
    ss += __shfl_xor(ss, 4);
    ss += __shfl_xor(ss, 8);
    ss += __shfl_xor(ss, 16);
    ss += __shfl_xor(ss, 32);
    __shared__ float red[4];
    if ((tid & 63) == 0) red[tid >> 6] = ss;
    __syncthreads();
    float tot = red[0] + red[1] + red[2] + red[3];
    float scale = rsqrtf(tot * (1.0f / (float)D_) + 1e-6f);
    float4 wv = ((const float4*)w)[tid];
    float4 o;
    o.x = wv.x * v.x * scale;
    o.y = wv.y * v.y * scale;
    o.z = wv.z * v.z * scale;
    o.w = wv.w * v.w * scale;
    st4(out + (size_t)t * D_ + tid * 4, o);
    if (last != nullptr && t == T_ - 1) ((float4*)last)[tid] = o;
}

// ---------------------------------------------------------------------------
// Fused: v = x + p0 + p1 (split-K reduce of O-proj + residual); write v to
// resid_out AND rmsnorm(v)*w -> bf16 xm.
// ---------------------------------------------------------------------------
__global__ __launch_bounds__(256) void rmsnorm_reduce2(
    const float* __restrict__ x, const float* __restrict__ p0, const float* __restrict__ p1,
    const float* __restrict__ w, float* __restrict__ resid_out, ushort* __restrict__ xm) {
    const int t = blockIdx.x;
    const int tid = threadIdx.x;
    const size_t base = (size_t)t * D_ + tid * 4;
    float4 v = *(const float4*)(x + base);
    float4 a = *(const float4*)(p0 + base);
    float4 b = *(const float4*)(p1 + base);
    v.x += a.x + b.x; v.y += a.y + b.y; v.z += a.z + b.z; v.w += a.w + b.w;
    st4(resid_out + base, v);
    float ss = v.x * v.x + v.y * v.y + v.z * v.z + v.w * v.w;
    ss += __shfl_xor(ss, 1);
    ss += __shfl_xor(ss, 2);
    ss += __shfl_xor(ss, 4);
    ss += __shfl_xor(ss, 8);
    ss += __shfl_xor(ss, 16);
    ss += __shfl_xor(ss, 32);
    __shared__ float red[4];
    if ((tid & 63) == 0) red[tid >> 6] = ss;
    __syncthreads();
    float tot = red[0] + red[1] + red[2] + red[3];
    float scale = rsqrtf(tot * (1.0f / (float)D_) + 1e-6f);
    float4 wv = ((const float4*)w)[tid];
    float4 o;
    o.x = wv.x * v.x * scale;
    o.y = wv.y * v.y * scale;
    o.z = wv.z * v.z * scale;
    o.w = wv.w * v.w * scale;
    st4(xm + base, o);
}

// out[i] += p0[i]+p1[i]+p2[i]+p3[i]  (split-K4 reduce, float4-strided)
__global__ __launch_bounds__(256) void add4_kernel(float* __restrict__ out,
                                                   const float* __restrict__ p,
                                                   int n4slice) {
    const int i = blockIdx.x * 256 + threadIdx.x;  // float4 index
    const float4* p4 = (const float4*)p;
    float4 o = ((const float4*)out)[i];
    float4 a = p4[i], b = p4[i + n4slice], c = p4[i + 2 * n4slice], d = p4[i + 3 * n4slice];
    o.x += (a.x + b.x) + (c.x + d.x);
    o.y += (a.y + b.y) + (c.y + d.y);
    o.z += (a.z + b.z) + (c.z + d.z);
    o.w += (a.w + b.w) + (c.w + d.w);
    ((float4*)out)[i] = o;
}

// ---------------------------------------------------------------------------
// Token shift -> six bf16 activation buffers (GEMM A operands).
// ---------------------------------------------------------------------------
__global__ __launch_bounds__(256) void shift_kernel(
    const float* __restrict__ xn, const float* __restrict__ x_prev,
    const float* __restrict__ cr, const float* __restrict__ cw, const float* __restrict__ ck,
    const float* __restrict__ cv, const float* __restrict__ ca, const float* __restrict__ cg,
    ushort* __restrict__ xr, ushort* __restrict__ xw, ushort* __restrict__ xk,
    ushort* __restrict__ xv, ushort* __restrict__ xa, ushort* __restrict__ xg) {
    const int i = blockIdx.x * 256 + threadIdx.x;  // float4 index over T*256
    const int t = i >> 8, j = i & 255;
    const float4* xn4 = (const float4*)xn;
    float4 cur = xn4[i];
    float4 prev = (t == 0) ? ((const float4*)x_prev)[j] : xn4[i - 256];
    float4 xx;
    xx.x = prev.x - cur.x;
    xx.y = prev.y - cur.y;
    xx.z = prev.z - cur.z;
    xx.w = prev.w - cur.w;
#define APPLY(dst, c)                                   \
    {                                                   \
        float4 cc = ((const float4*)c)[j];              \
        float4 o;                                       \
        o.x = cur.x + xx.x * cc.x;                      \
        o.y = cur.y + xx.y * cc.y;                      \
        o.z = cur.z + xx.z * cc.z;                      \
        o.w = cur.w + xx.w * cc.w;                      \
        st4(dst + (size_t)i * 4, o);                    \
    }
    APPLY(xr, cr)
    APPLY(xw, cw)
    APPLY(xk, ck)
    APPLY(xv, cv)
    APPLY(xa, ca)
    APPLY(xg, cg)
#undef APPLY
}

// ---------------------------------------------------------------------------
// Merged weight transpose + cast: all 15 weights in ONE launch.
// ---------------------------------------------------------------------------
struct TDesc { const float* in; ushort* out; int K, N, off; };
struct TPack { TDesc d[15]; };

__global__ __launch_bounds__(256) void transpose_cast_multi(TPack p) {
    __shared__ float tile[32][33];
    const int bid = blockIdx.x;
    int di = 0;
#pragma unroll
    for (int i = 1; i < 15; i++)
        if (bid >= p.d[i].off) di = i;
    const TDesc d = p.d[di];
    const int local = bid - d.off;
    const int nt = d.N >> 5;
    const int bx = local % nt, by = local / nt;
    const int tx = threadIdx.x & 31, ty = threadIdx.x >> 5;  // 32 x 8
    const int n0 = bx * 32, k0 = by * 32;
#pragma unroll
    for (int i = 0; i < 4; i++)
        tile[ty + i * 8][tx] = d.in[(size_t)(k0 + ty + i * 8) * d.N + n0 + tx];
    __syncthreads();
#pragma unroll
    for (int i = 0; i < 4; i++)
        d.out[(size_t)(n0 + ty + i * 8) * d.K + k0 + tx] = f2bf(tile[tx][ty + i * 8]);
}

// ---------------------------------------------------------------------------
// bf16 MFMA GEMM, 2-phase double-buffered global_load_lds pipeline.
// 128x128 tile, 4 waves 2x2, BK=32. PARTIAL=true: split-K slice z writes fp32
// partials at C + z*M*Ntot. Grids of exactly 8x16 (per z) get a 4x4-supertile
// XCD swizzle: xcd = linear_bid % 8 (z-stride 128 == 0 mod 8), so each XCD's
// 16 blocks form a 4x4 tile square whose A/B panels fit its private L2.
// epi: 0 none, 1 += res.
// ---------------------------------------------------------------------------
template <typename OutT, bool PARTIAL>
__global__ __launch_bounds__(256) void mfma_gemm(
    const ushort* __restrict__ A, const ushort* __restrict__ BT, OutT* __restrict__ C,
    const float* res, int M, int Ntot, int K, int klen, int epi) {
    __shared__ ushort As[2][128 * 32];
    __shared__ ushort Bs[2][128 * 32];
    const int tid = threadIdx.x;
    const int wave = tid >> 6, lane = tid & 63;
    const int wr = wave >> 1, wc = wave & 1;
    const int lrow = lane & 15, quad = lane >> 4;
    int bx = blockIdx.x, by = blockIdx.y;
    if (gridDim.x == 8 && gridDim.y == 16) {
        const int bid = by * 8 + bx;
        const int k = bid & 7, i = bid >> 3;
        bx = ((k & 1) << 2) + (i & 3);
        by = ((k >> 1) << 2) + (i >> 2);
    }
    const int m0 = by * 128, n0 = bx * 128;
    const int kbase = blockIdx.z * klen;
    const int srow = lane >> 2;
    const int scol = (lane & 3) << 3;

    f32x4 acc[4][4] = {};

    auto stage = [&](int buf, int kk) {
#pragma unroll
        for (int j = 0; j < 2; j++) {
            const int chunk = 2 * wave + j;  // 0..7
            const ushort* ga = A + (size_t)(m0 + chunk * 16 + srow) * K + kk + scol;
            __builtin_amdgcn_global_load_lds((glb_u32_t*)ga,
                                             (lds_u32_t*)&As[buf][chunk * 512], 16, 0, 0);
            const int brow = n0 + chunk * 16 + srow;
            if (brow < Ntot) {
                const ushort* gb = BT + (size_t)brow * K + kk + scol;
                __builtin_amdgcn_global_load_lds((glb_u32_t*)gb,
                                                 (lds_u32_t*)&Bs[buf][chunk * 512], 16, 0, 0);
            }
        }
    };

    stage(0, kbase);
    __syncthreads();
    int cur = 0;
    for (int k0 = kbase; k0 < kbase + klen; k0 += 32) {
        if (k0 + 32 < kbase + klen) stage(cur ^ 1, k0 + 32);
        bf16x8 af[4], bfr[4];
#pragma unroll
        for (int mi = 0; mi < 4; mi++)
            af[mi] = *(const bf16x8*)&As[cur][(wr * 64 + mi * 16 + lrow) * 32 + quad * 8];
#pragma unroll
        for (int ni = 0; ni < 4; ni++)
            bfr[ni] = *(const bf16x8*)&Bs[cur][(wc * 64 + ni * 16 + lrow) * 32 + quad * 8];
#pragma unroll
        for (int mi = 0; mi < 4; mi++)
#pragma unroll
            for (int ni = 0; ni < 4; ni++)
                acc[mi][ni] = __builtin_amdgcn_mfma_f32_16x16x32_bf16(af[mi], bfr[ni], acc[mi][ni], 0, 0, 0);
        __syncthreads();
        cur ^= 1;
    }

    const size_t zoff = PARTIAL ? (size_t)blockIdx.z * M * Ntot : 0;
#pragma unroll
    for (int mi = 0; mi < 4; mi++) {
#pragma unroll
        for (int r = 0; r < 4; r++) {
            const int row = m0 + wr * 64 + mi * 16 + quad * 4 + r;
#pragma unroll
            for (int ni = 0; ni < 4; ni++) {
                const int col = n0 + wc * 64 + ni * 16 + lrow;
                if (col < Ntot) {
                    const size_t idx = (size_t)row * Ntot + col;
                    float val = acc[mi][ni][r];
                    if constexpr (PARTIAL) {
                        ((float*)C)[idx + zoff] = val;
                    } else {
                        if (epi == 1) val += res[idx];
                        if constexpr (sizeof(OutT) == 2) C[idx] = (OutT)f2bf(val);
                        else C[idx] = (OutT)val;
                    }
                }
            }
        }
    }
}

// ---------------------------------------------------------------------------
// Multi-GEMM: z-indexed descriptors, same 2-phase pipeline. Non-atomic.
// epi: 0 none, 3 tanh, 4 sig, 5 sig(bias+v), 6 exp(-e^-.5*sig(bias+v)),
//      7 res+(res2-res)*sig(bias+v)
// ---------------------------------------------------------------------------
struct MMDesc {
    const ushort* A; const ushort* BT;
    float* Cf; ushort* Cb;
    const float* res; const float* res2; const float* bias;
    int Ntot, K, epi;
};
template <int NZ>
struct MMPack { MMDesc d[NZ]; };

template <int NZ>
__global__ __launch_bounds__(256) void mfma_gemm_multi(MMPack<NZ> p) {
    const MMDesc d = p.d[blockIdx.z];
    const int n0 = blockIdx.x * 128;
    if (n0 >= d.Ntot) return;  // uniform across block; no barrier crossed yet
    __shared__ ushort As[2][128 * 32];
    __shared__ ushort Bs[2][128 * 32];
    const int tid = threadIdx.x;
    const int wave = tid >> 6, lane = tid & 63;
    const int wr = wave >> 1, wc = wave & 1;
    const int lrow = lane & 15, quad = lane >> 4;
    const int m0 = blockIdx.y * 128;
    const int srow = lane >> 2;
    const int scol = (lane & 3) << 3;
    const int K = d.K, Ntot = d.Ntot;

    f32x4 acc[4][4] = {};

    auto stage = [&](int buf, int kk) {
#pragma unroll
        for (int j = 0; j < 2; j++) {
            const int chunk = 2 * wave + j;
            const ushort* ga = d.A + (size_t)(m0 + chunk * 16 + srow) * K + kk + scol;
            __builtin_amdgcn_global_load_lds((glb_u32_t*)ga,
                                             (lds_u32_t*)&As[buf][chunk * 512], 16, 0, 0);
            const int brow = n0 + chunk * 16 + srow;
            if (brow < Ntot) {
                const ushort* gb = d.BT + (size_t)brow * K + kk + scol;
                __builtin_amdgcn_global_load_lds((glb_u32_t*)gb,
                                                 (lds_u32_t*)&Bs[buf][chunk * 512], 16, 0, 0);
            }
        }
    };

    stage(0, 0);
    __syncthreads();
    int cur = 0;
    for (int k0 = 0; k0 < K; k0 += 32) {
        if (k0 + 32 < K) stage(cur ^ 1, k0 + 32);
        bf16x8 af[4], bfr[4];
#pragma unroll
        for (int mi = 0; mi < 4; mi++)
            af[mi] = *(const bf16x8*)&As[cur][(wr * 64 + mi * 16 + lrow) * 32 + quad * 8];
#pragma unroll
        for (int ni = 0; ni < 4; ni++)
            bfr[ni] = *(const bf16x8*)&Bs[cur][(wc * 64 + ni * 16 + lrow) * 32 + quad * 8];
#pragma unroll
        for (int mi = 0; mi < 4; mi++)
#pragma unroll
            for (int ni = 0; ni < 4; ni++)
                acc[mi][ni] = __builtin_amdgcn_mfma_f32_16x16x32_bf16(af[mi], bfr[ni], acc[mi][ni], 0, 0, 0);
        __syncthreads();
        cur ^= 1;
    }

#pragma unroll
    for (int mi = 0; mi < 4; mi++) {
#pragma unroll
        for (int r = 0; r < 4; r++) {
            const int row = m0 + wr * 64 + mi * 16 + quad * 4 + r;
#pragma unroll
            for (int ni = 0; ni < 4; ni++) {
                const int col = n0 + wc * 64 + ni * 16 + lrow;
                if (col < Ntot) {
                    const size_t idx = (size_t)row * Ntot + col;
                    float val = acc[mi][ni][r];
                    switch (d.epi) {
                        case 3: val = tanhf(val); break;
                        case 4: val = sigf(val); break;
                        case 5: val = sigf(d.bias[col] + val); break;
                        case 6: val = __expf(-0.60653065971263342f * sigf(d.bias[col] + val)); break;
                        case 7: {
                            float vr = d.res[idx];
                            val = vr + (d.res2[idx] - vr) * sigf(d.bias[col] + val);
                        } break;
                        default: break;
                    }
                    if (d.Cb) d.Cb[idx] = f2bf(val);
                    else d.Cf[idx] = val;
                }
            }
        }
    }
}

// ---------------------------------------------------------------------------
// kk = normalize_per_head(k * k_k); mb = -kk*a_sig; k *= (1+(a-1)*k_a).
// ---------------------------------------------------------------------------
__global__ __launch_bounds__(256) void kk_kernel(float* __restrict__ k,
                                                 const float* __restrict__ a_sig,
                                                 const float* __restrict__ k_k,
                                                 const float* __restrict__ k_a,
                                                 float* __restrict__ kk,
                                                 float* __restrict__ mb) {
    const int b = blockIdx.x * 4 + (threadIdx.x >> 6);
    const int t = b >> 4, h = b & 15;
    const int lane = threadIdx.x & 63;
    const size_t idx = (size_t)t * D_ + h * N_ + lane;
    const int wi = h * N_ + lane;
    const float kraw = k[idx];
    const float kv = kraw * k_k[wi];
    float ss = kv * kv;
    ss += __shfl_xor(ss, 1);
    ss += __shfl_xor(ss, 2);
    ss += __shfl_xor(ss, 4);
    ss += __shfl_xor(ss, 8);
    ss += __shfl_xor(ss, 16);
    ss += __shfl_xor(ss, 32);
    const float nrm = fmaxf(sqrtf(ss), 1e-12f);
    const float kkn = kv / nrm;
    kk[idx] = kkn;
    mb[idx] = -kkn * a_sig[idx];
    k[idx] = kraw * (1.0f + (a_sig[idx] - 1.0f) * k_a[wi]);
}

// ---------------------------------------------------------------------------
// Chunked scan pass 1: lane = row, register state; reg-staged 2-slot LDS ring.
// ---------------------------------------------------------------------------
#define FOR16(M) M(0) M(1) M(2) M(3) M(4) M(5) M(6) M(7) \
                 M(8) M(9) M(10) M(11) M(12) M(13) M(14) M(15)

__global__ __launch_bounds__(64, 1) void scan_pass1(
    const float* __restrict__ gR, const float* __restrict__ gD, const float* __restrict__ gK,
    const float* __restrict__ gV, const float* __restrict__ gKK, const float* __restrict__ gMB,
    float* __restrict__ Pbuf, float* __restrict__ Lbuf,
    float* __restrict__ zbuf, float* __restrict__ olbuf) {
    const int bid = blockIdx.x;
    const bool isp = bid >= NCHUNK * H_;  // role = high bit
    const int sub = isp ? bid - NCHUNK * H_ : bid;
    const int h = sub & 15;
    const int c = sub >> 4;
    const int lane = threadIdx.x;  // row index
    const int hb = h * N_;
    const int t0 = c * CLEN;
    const int tend = t0 + CLEN - 1;

    __shared__ __align__(16) unsigned char ring[2 * 2048];

    const int rsel = lane >> 4;
    const int sub4 = (lane & 15) << 2;
    const float* p1 = (rsel == 0 ? gR : rsel == 1 ? gD : rsel == 2 ? gK : gKK)
                      + (size_t)t0 * D_ + hb + sub4;
    const float* p2 = (rsel == 1 ? gV : gMB) + (size_t)t0 * D_ + hb + sub4;

    const float fid = isp ? 1.0f : 0.0f;
#define DECL(q) f32x4 s##q = {(lane == 4 * q + 0) ? fid : 0.0f, \
                              (lane == 4 * q + 1) ? fid : 0.0f, \
                              (lane == 4 * q + 2) ? fid : 0.0f, \
                              (lane == 4 * q + 3) ? fid : 0.0f};
    FOR16(DECL)
#undef DECL

    float* __restrict__ dotOut = isp ? zbuf : olbuf;

    float4 r0a, r0b, r1a, r1b, r2a, r2b, r3a, r3b;

#define LOADQ(qa, qb, tt) {                                                  \
        const size_t _adv = (size_t)((tt) - t0) * D_;                        \
        qa = *(const float4*)(p1 + _adv);                                    \
        qb = *(const float4*)(p2 + _adv); }
#define WRITEQ(sl, qa, qb) {                                                 \
        *(float4*)(ring + (sl) * 2048 + lane * 16) = qa;                     \
        *(float4*)(ring + (sl) * 2048 + 1024 + lane * 16) = qb; }
#define PA(q) { const f32x4 kk4 = sKKr[q]; sacc += s##q * kk4; }
#define PB(q) {                                                   \
        const f32x4 d4 = sDr[q];                                  \
        const f32x4 k4 = sKr[q];                                  \
        const f32x4 m4 = sMBr[q];                                 \
        const f32x4 r4 = sRr[q];                                  \
        s##q = s##q * d4 + (m4 * sap + k4 * vv);                  \
        oacc += s##q * r4;                                        \
    }
#define COMPUTE(sl, tt) {                                                    \
        const unsigned char* sb = (const unsigned char*)ring + (sl) * 2048;  \
        const f32x4* sRr = (const f32x4*)(sb);                               \
        const f32x4* sDr = (const f32x4*)(sb + 256);                         \
        const f32x4* sKr = (const f32x4*)(sb + 512);                         \
        const f32x4* sKKr = (const f32x4*)(sb + 768);                        \
        const f32x4* sMBr = (const f32x4*)(sb + 1024);                       \
        const float* sVr = (const float*)(sb + 1280);                        \
        f32x4 sacc = {0.f, 0.f, 0.f, 0.f};                                   \
        FOR16(PA)                                                            \
        const float sap = (sacc.x + sacc.y) + (sacc.z + sacc.w);             \
        const float vv = isp ? 0.0f : sVr[lane];                             \
        f32x4 oacc = {0.f, 0.f, 0.f, 0.f};                                   \
        FOR16(PB)                                                            \
        dotOut[(size_t)(tt) * D_ + hb + lane] =                              \
            (oacc.x + oacc.y) + (oacc.z + oacc.w); }

    // prologue: 4-deep register pipeline; slot0 primed with t0
    LOADQ(r0a, r0b, t0)
    LOADQ(r1a, r1b, t0 + 1)
    LOADQ(r2a, r2b, t0 + 2)
    LOADQ(r3a, r3b, t0 + 3)
    WRITEQ(0, r0a, r0b)

    for (int t = t0; t < t0 + CLEN; t += 4) {
        WRITEQ(1, r1a, r1b)                                    // data t+1
        LOADQ(r0a, r0b, (t + 4 > tend ? tend : t + 4))
        COMPUTE(0, t)
        WRITEQ(0, r2a, r2b)                                    // data t+2
        LOADQ(r1a, r1b, (t + 5 > tend ? tend : t + 5))
        COMPUTE(1, t + 1)
        WRITEQ(1, r3a, r3b)                                    // data t+3
        LOADQ(r2a, r2b, (t + 6 > tend ? tend : t + 6))
        COMPUTE(0, t + 2)
        WRITEQ(0, r0a, r0b)                                    // data t+4
        LOADQ(r3a, r3b, (t + 7 > tend ? tend : t + 7))
        COMPUTE(1, t + 3)
    }
#undef COMPUTE
#undef PB
#undef PA
#undef WRITEQ
#undef LOADQ

    float* __restrict__ sd = isp ? Pbuf : Lbuf;
    const size_t base = ((size_t)c * 16 + h) * 4096 + (size_t)lane * 64;
#define ST(q) *(f32x4*)(sd + base + 4 * q) = s##q;
    FOR16(ST)
#undef ST
}

// ---------------------------------------------------------------------------
// Serial chunk combine: S_{c+1} = S_c @ P_c + L_c, S_0 = state_in.
// ---------------------------------------------------------------------------
__global__ __launch_bounds__(256) void scan_combine(
    const float* __restrict__ state_in, const float* __restrict__ Pbuf,
    const float* __restrict__ Lbuf, float* __restrict__ SstT, float* __restrict__ state_out) {
    const int h = blockIdx.x >> 2, rg = blockIdx.x & 3;
    const int tid = threadIdx.x;
    const int i = tid >> 4, j4 = (tid & 15) << 2;
    const int gi = rg * 16 + i;
    __shared__ float Sl[16][68];
    __shared__ float Pl[64][68];

    float4 sv = *(const float4*)(state_in + (size_t)h * 4096 + gi * 64 + j4);
    *(float4*)&Sl[i][j4] = sv;
    __syncthreads();

    for (int c = 0; c < NCHUNK; c++) {
        const size_t cb = ((size_t)c * 16 + h) * 4096;
        float4 scur = *(const float4*)&Sl[i][j4];
        SstT[cb + (size_t)(j4 + 0) * 64 + gi] = scur.x;
        SstT[cb + (size_t)(j4 + 1) * 64 + gi] = scur.y;
        SstT[cb + (size_t)(j4 + 2) * 64 + gi] = scur.z;
        SstT[cb + (size_t)(j4 + 3) * 64 + gi] = scur.w;
#pragma unroll
        for (int q = 0; q < 4; q++) {
            const int pr = (tid >> 4) + q * 16;
            *(float4*)&Pl[pr][j4] = *(const float4*)(Pbuf + cb + (size_t)pr * 64 + j4);
        }
        __syncthreads();
        float4 acc = *(const float4*)(Lbuf + cb + (size_t)gi * 64 + j4);
#pragma unroll 8
        for (int m = 0; m < 64; m++) {
            const float smv = Sl[i][m];
            const float4 p4 = *(const float4*)&Pl[m][j4];
            acc.x = fmaf(smv, p4.x, acc.x);
            acc.y = fmaf(smv, p4.y, acc.y);
            acc.z = fmaf(smv, p4.z, acc.z);
            acc.w = fmaf(smv, p4.w, acc.w);
        }
        __syncthreads();
        *(float4*)&Sl[i][j4] = acc;
        __syncthreads();
    }
    *(float4*)(state_out + (size_t)h * 4096 + gi * 64 + j4) = *(const float4*)&Sl[i][j4];
}

// ---------------------------------------------------------------------------
// Fix pass: o[t] = o_local[t] + S_start_c @ z[t] (per head).
// ---------------------------------------------------------------------------
__global__ __launch_bounds__(256) void scan_fix(
    const float* __restrict__ zbuf, const float* __restrict__ olbuf,
    const float* __restrict__ SstT, float* __restrict__ o) {
    const int tg = blockIdx.x >> 4, h = blockIdx.x & 15;
    const int hb = h * N_;
    const int tid = threadIdx.x;
    const int tok = tid >> 4, i4 = (tid & 15) << 2;
    const int tbase = tg * 16;
    const int c = tbase >> 6;
    __shared__ float zl[16][68];
    __shared__ float Sl[64][68];

    *(float4*)&zl[tok][i4] = *(const float4*)(zbuf + (size_t)(tbase + tok) * D_ + hb + i4);
    const size_t cb = ((size_t)c * 16 + h) * 4096;
#pragma unroll
    for (int q = 0; q < 4; q++) {
        const int jr = (tid >> 4) + q * 16;
        *(float4*)&Sl[jr][i4] = *(const float4*)(SstT + cb + (size_t)jr * 64 + i4);
    }
    __syncthreads();
    float4 acc = *(const float4*)(olbuf + (size_t)(tbase + tok) * D_ + hb + i4);
#pragma unroll 8
    for (int j = 0; j < 64; j++) {
        const float zv = zl[tok][j];
        const float4 p4 = *(const float4*)&Sl[j][i4];
        acc.x = fmaf(zv, p4.x, acc.x);
        acc.y = fmaf(zv, p4.y, acc.y);
        acc.z = fmaf(zv, p4.z, acc.z);
        acc.w = fmaf(zv, p4.w, acc.w);
    }
    *(float4*)(o + (size_t)(tbase + tok) * D_ + hb + i4) = acc;
}

// ---------------------------------------------------------------------------
// bonus + gate: og = bf16((o + (sum_j r*k*r_k) * v) * g).
// ---------------------------------------------------------------------------
__global__ __launch_bounds__(256) void bonus_kernel(const float* __restrict__ o,
                                                    const float* __restrict__ r,
                                                    const float* __restrict__ k,
                                                    const float* __restrict__ v,
                                                    const float* __restrict__ g,
                                                    const float* __restrict__ r_k,
                                                    ushort* __restrict__ og) {
    const int b = blockIdx.x * 4 + (threadIdx.x >> 6);
    const int t = b >> 4, h = b & 15;
    const int lane = threadIdx.x & 63;
    const size_t idx = (size_t)t * D_ + h * N_ + lane;
    float c = r[idx] * k[idx] * r_k[h * N_ + lane];
    c += __shfl_xor(c, 1);
    c += __shfl_xor(c, 2);
    c += __shfl_xor(c, 4);
    c += __shfl_xor(c, 8);
    c += __shfl_xor(c, 16);
    c += __shfl_xor(c, 32);
    const float on = o[idx] + c * v[idx];
    og[idx] = f2bf(on * g[idx]);
}

// H[t,j] = silu(Z[t,j]) * Z[t,j+4096]  (Z = merged [gate|up], [T,8192] bf16)
__global__ __launch_bounds__(256) void mulz_kernel(const ushort* __restrict__ Z,
                                                   ushort* __restrict__ Hb) {
    const int idx = blockIdx.x * 256 + threadIdx.x;  // ushort4 index over T*1024
    const int t = idx >> 10;
    const int j = (idx & 1023) << 2;
    const ushort4 zg = *(const ushort4*)(Z + (size_t)t * 8192 + j);
    const ushort4 zu = *(const ushort4*)(Z + (size_t)t * 8192 + 4096 + j);
    ushort4 o;
    float g0 = bf2f(zg.x), g1 = bf2f(zg.y), g2 = bf2f(zg.z), g3 = bf2f(zg.w);
    o.x = f2bf(g0 * sigf(g0) * bf2f(zu.x));
    o.y = f2bf(g1 * sigf(g1) * bf2f(zu.y));
    o.z = f2bf(g2 * sigf(g2) * bf2f(zu.z));
    o.w = f2bf(g3 * sigf(g3) * bf2f(zu.w));
    *(ushort4*)(Hb + (size_t)t * 4096 + j) = o;
}

// ---------------------------------------------------------------------------
extern "C" void kernel_launch(void* const* d_in, const int* in_sizes, int n_in,
                              void* d_out, int out_size, void* d_ws, size_t ws_size,
                              hipStream_t stream) {
    const float* x      = (const float*)d_in[0];
    const float* x_prev = (const float*)d_in[1];
    const float* v_first= (const float*)d_in[2];
    const float* state  = (const float*)d_in[3];
    const float* ln1_w  = (const float*)d_in[4];
    const float* ln2_w  = (const float*)d_in[5];
    const float* x_r    = (const float*)d_in[6];
    const float* x_w    = (const float*)d_in[7];
    const float* x_k    = (const float*)d_in[8];
    const float* x_v    = (const float*)d_in[9];
    const float* x_a    = (const float*)d_in[10];
    const float* x_g    = (const float*)d_in[11];
    const float* w0     = (const float*)d_in[12];
    const float* w1     = (const float*)d_in[13];
    const float* w2     = (const float*)d_in[14];
    const float* a0     = (const float*)d_in[15];
    const float* a1     = (const float*)d_in[16];
    const float* a2     = (const float*)d_in[17];
    const float* v0     = (const float*)d_in[18];
    const float* v1     = (const float*)d_in[19];
    const float* v2     = (const float*)d_in[20];
    const float* g1     = (const float*)d_in[21];
    const float* g2     = (const float*)d_in[22];
    const float* k_k    = (const float*)d_in[23];
    const float* k_a    = (const float*)d_in[24];
    const float* r_k    = (const float*)d_in[25];
    const float* R_     = (const float*)d_in[26];
    const float* K_     = (const float*)d_in[27];
    const float* V_     = (const float*)d_in[28];
    const float* O_     = (const float*)d_in[29];
    const float* gate_w = (const float*)d_in[30];
    const float* up_w   = (const float*)d_in[31];
    const float* down_w = (const float*)d_in[32];

    float* ws = (float*)d_ws;
    const size_t U = (size_t)T_ * D_;  // 2M floats
    float* u_r  = ws;
    float* u_k  = ws + 1 * U;
    float* u_v  = ws + 2 * U;
    float* u_dc = ws + 3 * U;   // decay; later SstT
    float* u_kk = ws + 4 * U;   // kk;    later o (fix output)
    float* u_mb = ws + 5 * U;   // -kk*a; later O-proj partial 0
    float* u_g  = ws + 6 * U;   // g;     later O-proj partial 1
    float* u_ao = ws + 7 * U;   // a_sig; later Pbuf
    ushort* XB = (ushort*)(ws + 8 * U);
    const size_t TD = U;
    ushort* XR = XB + 0 * TD;
    ushort* XW = XB + 1 * TD;
    ushort* XK = XB + 2 * TD;
    ushort* XV = XB + 3 * TD;
    ushort* XA = XB + 4 * TD;
    ushort* XG = XB + 5 * TD;
    ushort* XM   = XB + 0 * TD;        // reuse XR after r-GEMM
    ushort* OG   = XB + 1 * TD;        // reuse XW after w-LoRA1
    ushort* Hbuf = XB + 2 * TD;        // MLP hidden, [T,F] bf16
    ushort* Zbuf = (ushort*)ws;        // merged [gate|up] [T,2F] bf16 (u_r..u_dc, dead)
    float* Opart = u_mb;               // O-proj split-K2 partials (u_mb,u_g dead)
    float* Dpart = ws;                 // down split-K4 partials (Zbuf dead post-mulz)
    float* Pbuf  = u_ao;
    float* Lbuf  = (float*)XB;
    float* zbuf  = (float*)(XB + 2 * TD);
    float* olbuf = (float*)(XB + 4 * TD);
    float* SstT  = u_dc;
    float* obuf  = u_kk;
    ushort* WT = (ushort*)(ws + 11 * U);
    const size_t DD = (size_t)D_ * D_;
    const size_t DF = (size_t)D_ * F_;
    ushort* WTR = WT;
    ushort* WTK = WTR + DD;
    ushort* WTV = WTK + DD;
    ushort* WTO = WTV + DD;
    ushort* WTG = WTO + DD;
    ushort* WTU = WTG + DF;
    ushort* WTD = WTU + DF;
    ushort* WTw1 = WTD + DF;
    ushort* WTw2 = WTw1 + 64 * 1024;
    ushort* WTa1 = WTw2 + 64 * 1024;
    ushort* WTa2 = WTa1 + 64 * 1024;
    ushort* WTv1 = WTa2 + 64 * 1024;
    ushort* WTv2 = WTv1 + 32 * 1024;
    ushort* WTg1 = WTv2 + 32 * 1024;
    ushort* WTg2 = WTg1 + 128 * 1024;
    ushort* Lw = WTg2 + 128 * 1024;
    ushort* La = Lw + (size_t)T_ * 64;
    ushort* Lv = La + (size_t)T_ * 64;
    ushort* Lg = Lv + (size_t)T_ * 32;

    float* out_x = (float*)d_out;
    float* out_xn_last = out_x + (size_t)T_ * D_;
    float* out_state = out_xn_last + D_;

    // --- all 15 weight transposes in ONE launch ---
    TPack tp;
    int toff = 0, ti = 0;
    auto addT = [&](const float* in, ushort* out, int K, int N) {
        tp.d[ti].in = in; tp.d[ti].out = out; tp.d[ti].K = K; tp.d[ti].N = N; tp.d[ti].off = toff;
        toff += (N / 32) * (K / 32); ++ti;
    };
    addT(R_, WTR, D_, D_);
    addT(K_, WTK, D_, D_);
    addT(V_, WTV, D_, D_);
    addT(O_, WTO, D_, D_);
    addT(gate_w, WTG, D_, F_);
    addT(up_w, WTU, D_, F_);
    addT(down_w, WTD, F_, D_);
    addT(w1, WTw1, D_, 64);
    addT(w2, WTw2, 64, D_);
    addT(a1, WTa1, D_, 64);
    addT(a2, WTa2, 64, D_);
    addT(v1, WTv1, D_, 32);
    addT(v2, WTv2, 32, D_);
    addT(g1, WTg1, D_, 128);
    addT(g2, WTg2, 128, D_);
    transpose_cast_multi<<<toff, 256, 0, stream>>>(tp);

    // 1. ln1 -> xn (in d_out) + xn_last
    rmsnorm_kernel<float><<<T_, 256, 0, stream>>>(x, ln1_w, out_x, out_xn_last);
    // 2. token shift -> bf16 xr..xg
    shift_kernel<<<T_, 256, 0, stream>>>(out_x, x_prev, x_r, x_w, x_k, x_v, x_a, x_g,
                                         XR, XW, XK, XV, XA, XG);
    // 3-6. r/k/v + 4 LoRA stage-1 GEMMs in ONE launch
    auto mkmm = [](const ushort* A, const ushort* BT, float* Cf, ushort* Cb,
                   const float* res, const float* res2, const float* bias,
                   int Ntot, int K, int epi) {
        MMDesc m{A, BT, Cf, Cb, res, res2, bias, Ntot, K, epi};
        return m;
    };
    MMPack<7> pa;
    pa.d[0] = mkmm(XR, WTR, u_r, nullptr, nullptr, nullptr, nullptr, D_, D_, 0);
    pa.d[1] = mkmm(XK, WTK, u_k, nullptr, nullptr, nullptr, nullptr, D_, D_, 0);
    pa.d[2] = mkmm(XV, WTV, u_v, nullptr, nullptr, nullptr, nullptr, D_, D_, 0);
    pa.d[3] = mkmm(XW, WTw1, nullptr, Lw, nullptr, nullptr, nullptr, 64,  D_, 3);  // tanh
    pa.d[4] = mkmm(XA, WTa1, nullptr, La, nullptr, nullptr, nullptr, 64,  D_, 0);
    pa.d[5] = mkmm(XV, WTv1, nullptr, Lv, nullptr, nullptr, nullptr, 32,  D_, 0);
    pa.d[6] = mkmm(XG, WTg1, nullptr, Lg, nullptr, nullptr, nullptr, 128, D_, 4);  // sigmoid
    mfma_gemm_multi<7><<<dim3(8, 16, 7), 256, 0, stream>>>(pa);
    // 7. LoRA stage-2 fused epilogues, ONE launch
    MMPack<4> pb;
    pb.d[0] = mkmm(Lw, WTw2, u_dc, nullptr, nullptr, nullptr, w0, D_, 64,  6);  // decay
    pb.d[1] = mkmm(La, WTa2, u_ao, nullptr, nullptr, nullptr, a0, D_, 64,  5);  // a_sig
    pb.d[2] = mkmm(Lv, WTv2, u_v,  nullptr, u_v, v_first,     v0, D_, 32,  7);  // v lerp
    pb.d[3] = mkmm(Lg, WTg2, u_g,  nullptr, nullptr, nullptr, nullptr, D_, 128, 0);  // g
    mfma_gemm_multi<4><<<dim3(8, 16, 4), 256, 0, stream>>>(pb);
    // 8. kk / mb / k-mod
    kk_kernel<<<T_ * H_ / 4, 256, 0, stream>>>(u_k, u_ao, k_k, k_a, u_kk, u_mb);
    // 9. chunked scan
    scan_pass1<<<NCHUNK * H_ * 2, 64, 0, stream>>>(u_r, u_dc, u_k, u_v, u_kk, u_mb,
                                                   Pbuf, Lbuf, zbuf, olbuf);
    scan_combine<<<H_ * 4, 256, 0, stream>>>(state, Pbuf, Lbuf, SstT, out_state);
    scan_fix<<<(T_ / 16) * H_, 256, 0, stream>>>(zbuf, olbuf, SstT, obuf);
    // 10. bonus + gate -> OG bf16
    bonus_kernel<<<T_ * H_ / 4, 256, 0, stream>>>(obuf, u_r, u_k, u_v, u_g, r_k, OG);
    // 11. O-proj split-K2 -> fp32 partials (u_mb/u_g dead), 256 blocks
    mfma_gemm<float, true><<<dim3(8, 16, 2), 256, 0, stream>>>(
        OG, WTO, Opart, nullptr, T_, D_, D_, 512, 0);
    // 12. fused: out_x = x + p0 + p1; ln2(out_x) -> XM bf16
    rmsnorm_reduce2<<<T_, 256, 0, stream>>>(x, Opart, Opart + U, ln2_w, out_x, XM);
    // 13. MLP: merged gate|up (N=8192, 1024 blocks), swiglu
    mfma_gemm<ushort, false><<<dim3(64, 16), 256, 0, stream>>>(
        XM, WTG, Zbuf, nullptr, T_, 2 * F_, D_, D_, 0);
    mulz_kernel<<<(T_ * (F_ / 4)) / 256, 256, 0, stream>>>(Zbuf, Hbuf);
    // 14. down split-K4 -> fp32 partials over dead Zbuf region, 512 blocks
    mfma_gemm<float, true><<<dim3(8, 16, 4), 256, 0, stream>>>(
        Hbuf, WTD, Dpart, nullptr, T_, D_, F_, 1024, 0);
    // 15. out_x += sum of 4 partials
    add4_kernel<<<(int)(U / 4 / 256), 256, 0, stream>>>(out_x, Dpart, (int)(U / 4));
}